// Round 2
// baseline (103.431 us; speedup 1.0000x reference)
//
#include <hip/hip_runtime.h>
#include <math.h>

#define NQ 4
#define DIM 16
#define K 512

// ---------------------------------------------------------------------------
// Kernel 1: per-wave GEMM, 4 rows per wave.
// pre_out[b][q] = dot(x[b], w[q]) + bias[q]
// Lanes split K=512 as 2x float4 each; w fragments loaded once per wave.
// Reduction: 2-stage compaction (7 shuffles/row instead of 24).
// ---------------------------------------------------------------------------
__global__ __launch_bounds__(256) void qnet_gemm(const float* __restrict__ x,
                                                 const float* __restrict__ w,
                                                 const float* __restrict__ bias,
                                                 float* __restrict__ pre_out,
                                                 int B) {
    const int wid  = (int)((blockIdx.x * blockDim.x + threadIdx.x) >> 6);
    const int lane = (int)(threadIdx.x & 63);
    const int row0 = wid * 4;
    if (row0 >= B) return;

    // w fragments: w[q][h*256 + lane*4 .. +3], resident once per wave (L1-hot)
    float4 wf[NQ][2];
#pragma unroll
    for (int q = 0; q < NQ; ++q) {
#pragma unroll
        for (int h = 0; h < 2; ++h)
            wf[q][h] = *(const float4*)(w + q * K + h * 256 + lane * 4);
    }

    float acc[4][NQ];
#pragma unroll
    for (int r = 0; r < 4; ++r) {
        int row = row0 + r;
        if (row >= B) row = B - 1;  // clamp (B%4==0 in practice)
        const float* xr = x + (size_t)row * K;
        float4 x0 = *(const float4*)(xr + lane * 4);
        float4 x1 = *(const float4*)(xr + 256 + lane * 4);
#pragma unroll
        for (int q = 0; q < NQ; ++q) {
            acc[r][q] = x0.x * wf[q][0].x + x0.y * wf[q][0].y
                      + x0.z * wf[q][0].z + x0.w * wf[q][0].w
                      + x1.x * wf[q][1].x + x1.y * wf[q][1].y
                      + x1.z * wf[q][1].z + x1.w * wf[q][1].w;
        }
    }

    // Compacting reduction: after this, lane holds sum for q = lane&3
    // over its 4-lane group; 4 more butterfly stages finish across the wave.
    const int l1 = lane & 1;
    const int l2 = lane & 2;
    float v[4];  // per row: lane's q=(lane&3) total
#pragma unroll
    for (int r = 0; r < 4; ++r) {
        float a01k = l1 ? acc[r][1] : acc[r][0];
        float a01s = l1 ? acc[r][0] : acc[r][1];
        a01k += __shfl_xor(a01s, 1, 64);
        float a23k = l1 ? acc[r][3] : acc[r][2];
        float a23s = l1 ? acc[r][2] : acc[r][3];
        a23k += __shfl_xor(a23s, 1, 64);
        float vk = l2 ? a23k : a01k;
        float vs = l2 ? a01k : a23k;
        vk += __shfl_xor(vs, 2, 64);
#pragma unroll
        for (int off = 4; off <= 32; off <<= 1)
            vk += __shfl_xor(vk, off, 64);
        v[r] = vk;
    }

    // Lanes 0..15: lane = r*4 + q writes pre_out[(row0+r)*4 + q] (64 B contiguous)
    if (lane < 16) {
        const int r = lane >> 2;
        const int q = lane & 3;
        float vr = (r == 0) ? v[0] : (r == 1) ? v[1] : (r == 2) ? v[2] : v[3];
        const int row = row0 + r;
        if (row < B) pre_out[(size_t)row * 4 + q] = vr + bias[q];
    }
}

// ---------------------------------------------------------------------------
// Kernel 2: one thread per batch row. 4-qubit statevector (16 complex amps)
// entirely in registers; all loops fully unrolled (compile-time indices).
// Qubit q maps to bit (3-q) of the amplitude index (q=0 is MSB).
// ---------------------------------------------------------------------------
__global__ __launch_bounds__(256) void qnet_circuit(const float* __restrict__ pre_out,
                                                    const float* __restrict__ u3p,
                                                    const float* __restrict__ post_w,
                                                    const float* __restrict__ post_b,
                                                    float* __restrict__ out,
                                                    int B) {
    int b = (int)(blockIdx.x * blockDim.x + threadIdx.x);
    if (b >= B) return;

    float4 p4 = *(const float4*)(pre_out + (size_t)b * 4);
    float pre[NQ] = {p4.x, p4.y, p4.z, p4.w};

    float ry[NQ], rz[NQ];
#pragma unroll
    for (int q = 0; q < NQ; ++q) {
        // tanh(z) = 1 - 2/(exp(2z)+1)  (fast: one __expf + one rcp)
        float z = pre[q] * 0.1f;
        float t = 1.0f - 2.0f / (__expf(2.0f * z) + 1.0f);
        float qi = t * 1.5707963267948966f;
        ry[q] = atanf(qi);
        rz[q] = atanf(qi * qi);
    }

    // After H on all 4 qubits of |0000>, state is uniformly 1/4 (real).
    float sr[DIM], si[DIM];
#pragma unroll
    for (int i = 0; i < DIM; ++i) { sr[i] = 0.25f; si[i] = 0.0f; }

    // RY(theta): [[c,-s],[s,c]] with c=cos(theta/2), s=sin(theta/2) (real gate)
#pragma unroll
    for (int q = 0; q < NQ; ++q) {
        float c, s;
        __sincosf(ry[q] * 0.5f, &s, &c);
        const int m = 1 << (3 - q);
#pragma unroll
        for (int i = 0; i < DIM; ++i) {
            if (i & m) continue;
            const int j = i | m;
            float r0 = sr[i], i0 = si[i], r1 = sr[j], i1 = si[j];
            sr[i] = c * r0 - s * r1;  si[i] = c * i0 - s * i1;
            sr[j] = s * r0 + c * r1;  si[j] = s * i0 + c * i1;
        }
    }

    // RZ(theta): diag(e^{-i t/2}, e^{+i t/2})
#pragma unroll
    for (int q = 0; q < NQ; ++q) {
        float c, s;
        __sincosf(rz[q] * 0.5f, &s, &c);
        const int m = 1 << (3 - q);
#pragma unroll
        for (int i = 0; i < DIM; ++i) {
            const float sg = (i & m) ? s : -s;   // multiply by (c, sg)
            float r = sr[i], im = si[i];
            sr[i] = c * r - sg * im;
            si[i] = c * im + sg * r;
        }
    }

    // CNOT ring step=1 then step=2, applied sequentially.
    const int cn_c[8] = {0, 1, 2, 3, 0, 1, 2, 3};
    const int cn_t[8] = {1, 2, 3, 0, 2, 3, 0, 1};
#pragma unroll
    for (int k = 0; k < 8; ++k) {
        const int cm = 1 << (3 - cn_c[k]);
        const int tm = 1 << (3 - cn_t[k]);
#pragma unroll
        for (int i = 0; i < DIM; ++i) {
            if ((i & cm) && !(i & tm)) {
                const int j = i | tm;
                float tr = sr[i]; sr[i] = sr[j]; sr[j] = tr;
                float ti = si[i]; si[i] = si[j]; si[j] = ti;
            }
        }
    }

    // U3(th,ph,la) = [[ct, -e^{i la} st], [e^{i ph} st, e^{i(ph+la)} ct]]
#pragma unroll
    for (int q = 0; q < NQ; ++q) {
        float th = u3p[q * 3 + 0], ph = u3p[q * 3 + 1], la = u3p[q * 3 + 2];
        float ct, st, cl, sl, cp, sp, cpl, spl;
        __sincosf(th * 0.5f, &st, &ct);
        __sincosf(la, &sl, &cl);
        __sincosf(ph, &sp, &cp);
        __sincosf(ph + la, &spl, &cpl);
        const float g01r = -cl * st, g01i = -sl * st;
        const float g10r = cp * st,  g10i = sp * st;
        const float g11r = cpl * ct, g11i = spl * ct;
        const int m = 1 << (3 - q);
#pragma unroll
        for (int i = 0; i < DIM; ++i) {
            if (i & m) continue;
            const int j = i | m;
            float r0 = sr[i], i0 = si[i], r1 = sr[j], i1 = si[j];
            sr[i] = ct * r0 + g01r * r1 - g01i * i1;
            si[i] = ct * i0 + g01r * i1 + g01i * r1;
            sr[j] = g10r * r0 - g10i * i0 + g11r * r1 - g11i * i1;
            si[j] = g10r * i0 + g10i * r0 + g11r * i1 + g11i * r1;
        }
    }

    // Z expectation per qubit: sum_{idx} |amp|^2 * (bit(3-q) ? -1 : +1)
    float ex[NQ] = {0.f, 0.f, 0.f, 0.f};
#pragma unroll
    for (int i = 0; i < DIM; ++i) {
        const float p2 = sr[i] * sr[i] + si[i] * si[i];
#pragma unroll
        for (int q = 0; q < NQ; ++q)
            ex[q] += (i & (1 << (3 - q))) ? -p2 : p2;
    }

    float o0 = post_b[0], o1 = post_b[1];
#pragma unroll
    for (int q = 0; q < NQ; ++q) {
        o0 += ex[q] * post_w[q];       // post_w row 0
        o1 += ex[q] * post_w[4 + q];   // post_w row 1
    }
    *(float2*)(out + (size_t)b * 2) = make_float2(o0, o1);
}

extern "C" void kernel_launch(void* const* d_in, const int* in_sizes, int n_in,
                              void* d_out, int out_size, void* d_ws, size_t ws_size,
                              hipStream_t stream) {
    const float* x      = (const float*)d_in[0];  // [B, 512]
    const float* pre_w  = (const float*)d_in[1];  // [4, 512]
    const float* pre_b  = (const float*)d_in[2];  // [4]
    const float* u3p    = (const float*)d_in[3];  // [4, 3]
    const float* post_w = (const float*)d_in[4];  // [2, 4]
    const float* post_b = (const float*)d_in[5];  // [2]
    float* out = (float*)d_out;                   // [B, 2]

    const int B = in_sizes[0] / K;                // 32768
    float* pre_out = (float*)d_ws;                // [B, 4] scratch

    // Kernel 1: 4 rows per wave, 4 waves per block -> 16 rows/block.
    {
        int rows_per_block = 16;
        int blocks = (B + rows_per_block - 1) / rows_per_block;
        qnet_gemm<<<blocks, 256, 0, stream>>>(x, pre_w, pre_b, pre_out, B);
    }
    // Kernel 2: one thread per row.
    {
        int threads = 256;
        int blocks = (B + threads - 1) / threads;
        qnet_circuit<<<blocks, threads, 0, stream>>>(pre_out, u3p, post_w, post_b, out, B);
    }
}

// Round 3
// 102.251 us; speedup vs baseline: 1.0115x; 1.0115x over previous
//
#include <hip/hip_runtime.h>
#include <math.h>

#define NQ 4
#define DIM 16
#define K 512

// ---------------------------------------------------------------------------
// Fused kernel: GEMM + quantum circuit + post-projection in one launch.
//
// Block = 256 threads = 4 waves; each wave computes pre-activations for 4
// batch rows (16 rows/block, 2048 blocks at B=32768).  Per-wave GEMM: lanes
// split K=512 as 2x float4; w fragments (8 KB total) are L1-hot.  A 2-stage
// compacting shuffle reduction (7 shuffles/row) leaves lane (r*4+q) holding
// pre[row0+r][q]; lanes 0..15 stage 16 floats to LDS.  After one
// __syncthreads, threads 0..15 each run the full 4-qubit register-resident
// statevector circuit for one row and write the 2 outputs directly.
// ---------------------------------------------------------------------------
__global__ __launch_bounds__(256) void qnet_fused(const float* __restrict__ x,
                                                  const float* __restrict__ w,
                                                  const float* __restrict__ bias,
                                                  const float* __restrict__ u3p,
                                                  const float* __restrict__ post_w,
                                                  const float* __restrict__ post_b,
                                                  float* __restrict__ out,
                                                  int B) {
    __shared__ float lds_pre[64];   // [row_local(16)][q(4)]

    const int wave = (int)(threadIdx.x >> 6);
    const int lane = (int)(threadIdx.x & 63);
    const int block_row0 = (int)blockIdx.x * 16;
    const int row0 = block_row0 + wave * 4;

    // ---- GEMM phase -------------------------------------------------------
    if (row0 < B) {
        float4 wf[NQ][2];
#pragma unroll
        for (int q = 0; q < NQ; ++q) {
#pragma unroll
            for (int h = 0; h < 2; ++h)
                wf[q][h] = *(const float4*)(w + q * K + h * 256 + lane * 4);
        }

        float acc[4][NQ];
#pragma unroll
        for (int r = 0; r < 4; ++r) {
            int row = row0 + r;
            if (row >= B) row = B - 1;   // clamp (B%16==0 in practice)
            const float* xr = x + (size_t)row * K;
            float4 x0 = *(const float4*)(xr + lane * 4);
            float4 x1 = *(const float4*)(xr + 256 + lane * 4);
#pragma unroll
            for (int q = 0; q < NQ; ++q) {
                acc[r][q] = x0.x * wf[q][0].x + x0.y * wf[q][0].y
                          + x0.z * wf[q][0].z + x0.w * wf[q][0].w
                          + x1.x * wf[q][1].x + x1.y * wf[q][1].y
                          + x1.z * wf[q][1].z + x1.w * wf[q][1].w;
            }
        }

        // Compacting reduction: lane ends with q=(lane&3) total for its row.
        const int l1 = lane & 1;
        const int l2 = lane & 2;
        float v[4];
#pragma unroll
        for (int r = 0; r < 4; ++r) {
            float a01k = l1 ? acc[r][1] : acc[r][0];
            float a01s = l1 ? acc[r][0] : acc[r][1];
            a01k += __shfl_xor(a01s, 1, 64);
            float a23k = l1 ? acc[r][3] : acc[r][2];
            float a23s = l1 ? acc[r][2] : acc[r][3];
            a23k += __shfl_xor(a23s, 1, 64);
            float vk = l2 ? a23k : a01k;
            float vs = l2 ? a01k : a23k;
            vk += __shfl_xor(vs, 2, 64);
#pragma unroll
            for (int off = 4; off <= 32; off <<= 1)
                vk += __shfl_xor(vk, off, 64);
            v[r] = vk;
        }

        if (lane < 16) {
            const int r = lane >> 2;
            const int q = lane & 3;
            float vr = (r == 0) ? v[0] : (r == 1) ? v[1] : (r == 2) ? v[2] : v[3];
            lds_pre[wave * 16 + lane] = vr + bias[q];
        }
    }
    __syncthreads();

    // ---- Circuit phase: threads 0..15, one row each -----------------------
    const int t = (int)threadIdx.x;
    if (t >= 16) return;
    const int b = block_row0 + t;
    if (b >= B) return;

    float pre[NQ] = {lds_pre[t * 4 + 0], lds_pre[t * 4 + 1],
                     lds_pre[t * 4 + 2], lds_pre[t * 4 + 3]};

    float ry[NQ], rz[NQ];
#pragma unroll
    for (int q = 0; q < NQ; ++q) {
        // tanh(z) = 1 - 2/(exp(2z)+1)
        float z = pre[q] * 0.1f;
        float tnh = 1.0f - 2.0f / (__expf(2.0f * z) + 1.0f);
        float qi = tnh * 1.5707963267948966f;
        ry[q] = atanf(qi);
        rz[q] = atanf(qi * qi);
    }

    // H^4 |0000> = uniform 1/4 (real).
    float sr[DIM], si[DIM];
#pragma unroll
    for (int i = 0; i < DIM; ++i) { sr[i] = 0.25f; si[i] = 0.0f; }

    // RY
#pragma unroll
    for (int q = 0; q < NQ; ++q) {
        float c, s;
        __sincosf(ry[q] * 0.5f, &s, &c);
        const int m = 1 << (3 - q);
#pragma unroll
        for (int i = 0; i < DIM; ++i) {
            if (i & m) continue;
            const int j = i | m;
            float r0 = sr[i], i0 = si[i], r1 = sr[j], i1 = si[j];
            sr[i] = c * r0 - s * r1;  si[i] = c * i0 - s * i1;
            sr[j] = s * r0 + c * r1;  si[j] = s * i0 + c * i1;
        }
    }

    // RZ
#pragma unroll
    for (int q = 0; q < NQ; ++q) {
        float c, s;
        __sincosf(rz[q] * 0.5f, &s, &c);
        const int m = 1 << (3 - q);
#pragma unroll
        for (int i = 0; i < DIM; ++i) {
            const float sg = (i & m) ? s : -s;
            float r = sr[i], im = si[i];
            sr[i] = c * r - sg * im;
            si[i] = c * im + sg * r;
        }
    }

    // CNOT ring step=1 then step=2
    const int cn_c[8] = {0, 1, 2, 3, 0, 1, 2, 3};
    const int cn_t[8] = {1, 2, 3, 0, 2, 3, 0, 1};
#pragma unroll
    for (int k = 0; k < 8; ++k) {
        const int cm = 1 << (3 - cn_c[k]);
        const int tm = 1 << (3 - cn_t[k]);
#pragma unroll
        for (int i = 0; i < DIM; ++i) {
            if ((i & cm) && !(i & tm)) {
                const int j = i | tm;
                float tr = sr[i]; sr[i] = sr[j]; sr[j] = tr;
                float ti = si[i]; si[i] = si[j]; si[j] = ti;
            }
        }
    }

    // U3
#pragma unroll
    for (int q = 0; q < NQ; ++q) {
        float th = u3p[q * 3 + 0], ph = u3p[q * 3 + 1], la = u3p[q * 3 + 2];
        float ct, st, cl, sl, cp, sp, cpl, spl;
        __sincosf(th * 0.5f, &st, &ct);
        __sincosf(la, &sl, &cl);
        __sincosf(ph, &sp, &cp);
        __sincosf(ph + la, &spl, &cpl);
        const float g01r = -cl * st, g01i = -sl * st;
        const float g10r = cp * st,  g10i = sp * st;
        const float g11r = cpl * ct, g11i = spl * ct;
        const int m = 1 << (3 - q);
#pragma unroll
        for (int i = 0; i < DIM; ++i) {
            if (i & m) continue;
            const int j = i | m;
            float r0 = sr[i], i0 = si[i], r1 = sr[j], i1 = si[j];
            sr[i] = ct * r0 + g01r * r1 - g01i * i1;
            si[i] = ct * i0 + g01r * i1 + g01i * r1;
            sr[j] = g10r * r0 - g10i * i0 + g11r * r1 - g11i * i1;
            si[j] = g10r * i0 + g10i * r0 + g11r * i1 + g11i * r1;
        }
    }

    // Z expectations + post projection
    float ex[NQ] = {0.f, 0.f, 0.f, 0.f};
#pragma unroll
    for (int i = 0; i < DIM; ++i) {
        const float p2 = sr[i] * sr[i] + si[i] * si[i];
#pragma unroll
        for (int q = 0; q < NQ; ++q)
            ex[q] += (i & (1 << (3 - q))) ? -p2 : p2;
    }

    float o0 = post_b[0], o1 = post_b[1];
#pragma unroll
    for (int q = 0; q < NQ; ++q) {
        o0 += ex[q] * post_w[q];
        o1 += ex[q] * post_w[4 + q];
    }
    *(float2*)(out + (size_t)b * 2) = make_float2(o0, o1);
}

extern "C" void kernel_launch(void* const* d_in, const int* in_sizes, int n_in,
                              void* d_out, int out_size, void* d_ws, size_t ws_size,
                              hipStream_t stream) {
    const float* x      = (const float*)d_in[0];  // [B, 512]
    const float* pre_w  = (const float*)d_in[1];  // [4, 512]
    const float* pre_b  = (const float*)d_in[2];  // [4]
    const float* u3p    = (const float*)d_in[3];  // [4, 3]
    const float* post_w = (const float*)d_in[4];  // [2, 4]
    const float* post_b = (const float*)d_in[5];  // [2]
    float* out = (float*)d_out;                   // [B, 2]

    const int B = in_sizes[0] / K;                // 32768

    const int rows_per_block = 16;
    const int blocks = (B + rows_per_block - 1) / rows_per_block;
    qnet_fused<<<blocks, 256, 0, stream>>>(x, pre_w, pre_b, u3p, post_w, post_b, out, B);
}